// Round 16
// baseline (2432.524 us; speedup 1.0000x reference)
//
#include <hip/hip_runtime.h>
#include <cstdint>
#include <cstddef>

// ---------------- model constants ----------------
#define B_    256
#define T_    90
#define K_    17
#define NPER  1530              // T_*K_
#define NN    (B_*NPER)         // 391680 nodes
#define H_    64
#define LH    512
#define G4    2048              // 4*LH
#define G8    4096              // both directions
#define IN1   1122              // K_*(H_+2)
#define IN1P  1152              // padded to mult of 32
#define SEQR  (B_*T_)           // 23040
#define OUT_  57

typedef unsigned short u16;
typedef __attribute__((ext_vector_type(8))) short short8;
typedef __attribute__((ext_vector_type(4))) float f32x4;

__device__ __forceinline__ float b2f(u16 u){ union{unsigned i; float f;} x; x.i=((unsigned)u)<<16; return x.f; }
__device__ __forceinline__ u16 f2b(float f){ union{float f; unsigned i;} x; x.f=f; unsigned r=x.i+0x7fffu+((x.i>>16)&1u); return (u16)(r>>16); }
__device__ __forceinline__ float sigm(float v){ return 1.f/(1.f+__expf(-v)); }
__device__ __forceinline__ float tanh_(float v){ return 2.f*sigm(2.f*v)-1.f; }

// ---------------- diagnostic sentinel (ws too small) ----------------
__global__ __launch_bounds__(256)
void stg_sentinel(float* __restrict__ out, int n){
  int i=blockIdx.x*256+threadIdx.x;
  if(i<n) out[i]=123.0f;
}

// ---------------- prep kernels ----------------
__global__ __launch_bounds__(256)
void stg_permute_w(const float* __restrict__ src, u16* __restrict__ dst, int Ks, int Kd){
  size_t idx=(size_t)blockIdx.x*256+threadIdx.x;
  int rn=(int)(idx/Kd), kk=(int)(idx%Kd);
  int j=rn>>2, G=rn&3, ro=G*LH+j;
  dst[idx] = (kk<Ks)? f2b(src[(size_t)ro*Ks+kk]) : (u16)0;
}

__global__ __launch_bounds__(256)
void stg_prep_bias(const float* __restrict__ bih, const float* __restrict__ bhh, float* __restrict__ dst){
  int rn=blockIdx.x*256+threadIdx.x;
  int j=rn>>2, G=rn&3, ro=G*LH+j;
  dst[rn]=bih[ro]+bhh[ro];
}

__global__ __launch_bounds__(256)
void stg_transpose_pad(const float* __restrict__ src, u16* __restrict__ dst, int R, int C, int Crows){
  size_t idx=(size_t)blockIdx.x*256+threadIdx.x;
  int c=(int)(idx/R), r=(int)(idx%R);
  dst[idx] = (c<C)? f2b(src[(size_t)r*C+c]) : (u16)0;
  (void)Crows;
}

// ---------------- GAT ----------------
// xp + fused attention scores (wave == node, lane == channel)
__global__ __launch_bounds__(256)
void stg_gat1_xp(const float* __restrict__ x, const float* __restrict__ W, u16* __restrict__ xp,
                 const float* __restrict__ as, const float* __restrict__ ad,
                 float* __restrict__ ssrc, float* __restrict__ sdst){
  size_t idx=(size_t)blockIdx.x*256+threadIdx.x;
  size_t n=idx>>6; int c=idx&63;
  float v=x[n*2]*W[c]+x[n*2+1]*W[64+c];
  u16 vb16=f2b(v);
  xp[idx]=vb16;
  float vb=b2f(vb16);
  float s1=vb*as[c], s2=vb*ad[c];
  #pragma unroll
  for(int m=1;m<64;m<<=1){ s1+=__shfl_xor(s1,m); s2+=__shfl_xor(s2,m); }
  if(c==0){ ssrc[n]=s1; sdst[n]=s2; }
}

__global__ __launch_bounds__(256)
void stg_scores(const u16* __restrict__ xp, const float* __restrict__ as, const float* __restrict__ ad,
                float* __restrict__ ssrc, float* __restrict__ sdst){
  const int lane=threadIdx.x&63;
  const size_t n=(size_t)blockIdx.x*4+(threadIdx.x>>6);
  float v=b2f(xp[n*64+lane]);
  float s1=v*as[lane], s2=v*ad[lane];
  #pragma unroll
  for(int m=1;m<64;m<<=1){ s1+=__shfl_xor(s1,m); s2+=__shfl_xor(s2,m); }
  if(lane==0){ ssrc[n]=s1; sdst[n]=s2; }
}

// skeleton adjacency derived from CONNS (undirected)
__constant__ int c_deg[17]={2,3,3,2,2,4,4,2,2,1,1,3,3,2,2,1,1};
__constant__ int c_adj[17][4]={{1,2,0,0},{2,0,3,0},{1,0,4,0},{1,5,0,0},{2,6,0,0},
 {11,6,7,3},{12,5,8,4},{5,9,0,0},{6,10,0,0},{7,0,0,0},{8,0,0,0},
 {13,12,5,0},{14,11,6,0},{15,11,0,0},{16,12,0,0},{13,0,0,0},{14,0,0,0}};

// wave per dst node; lane = channel. FULLY UNROLLED 7 slots, all regs (no scratch).
__global__ __launch_bounds__(256)
void stg_gat_agg(const u16* __restrict__ xp, const float* __restrict__ ssrc, const float* __restrict__ sdst,
                 const float* __restrict__ bias, u16* __restrict__ out){
  const int lane=threadIdx.x&63;
  const int n=blockIdx.x*4+(threadIdx.x>>6);
  const int r=n%NPER, t=r/K_, k=r%K_;
  const int dg=c_deg[k];
  const int base=n-k;
  const int nb0=n;
  const int nb1=(t>0)?      n-K_ : n;  const bool v1=(t>0);
  const int nb2=(t<T_-1)?   n+K_ : n;  const bool v2=(t<T_-1);
  const int nb3=base+c_adj[k][0];
  const int nb4=base+c_adj[k][1];      const bool v4=(dg>1);
  const int nb5=base+c_adj[k][2];      const bool v5=(dg>2);
  const int nb6=base+c_adj[k][3];      const bool v6=(dg>3);
  const float sd=sdst[n];
  const float NEG=-1e30f;
  auto lrelu=[](float v){ return v>0.f? v : 0.2f*v; };
  float e0=lrelu(ssrc[nb0]+sd);
  float e1=v1? lrelu(ssrc[nb1]+sd) : NEG;
  float e2=v2? lrelu(ssrc[nb2]+sd) : NEG;
  float e3=    lrelu(ssrc[nb3]+sd);
  float e4=v4? lrelu(ssrc[nb4]+sd) : NEG;
  float e5=v5? lrelu(ssrc[nb5]+sd) : NEG;
  float e6=v6? lrelu(ssrc[nb6]+sd) : NEG;
  float mx=fmaxf(fmaxf(fmaxf(e0,e1),fmaxf(e2,e3)),fmaxf(fmaxf(e4,e5),e6));
  float w0=__expf(e0-mx), w1=__expf(e1-mx), w2=__expf(e2-mx), w3=__expf(e3-mx);
  float w4=__expf(e4-mx), w5=__expf(e5-mx), w6=__expf(e6-mx);
  const float inv=1.f/(w0+w1+w2+w3+w4+w5+w6);
  float acc = w0*b2f(xp[(size_t)nb0*64+lane])
            + w1*b2f(xp[(size_t)nb1*64+lane])
            + w2*b2f(xp[(size_t)nb2*64+lane])
            + w3*b2f(xp[(size_t)nb3*64+lane])
            + w4*b2f(xp[(size_t)nb4*64+lane])
            + w5*b2f(xp[(size_t)nb5*64+lane])
            + w6*b2f(xp[(size_t)nb6*64+lane]);
  out[(size_t)n*64+lane]=f2b(acc*inv+bias[lane]);
}

// ---------------- batch norm (deterministic 2-stage) ----------------
__global__ __launch_bounds__(256)
void stg_bn_part(const u16* __restrict__ in, float* __restrict__ part){
  const int c=threadIdx.x&63, sub=threadIdx.x>>6;
  float s=0.f,q=0.f;
  for(size_t n=(size_t)blockIdx.x*4+sub; n<NN; n+=1024){
    float v=b2f(in[n*64+c]); s+=v; q+=v*v;
  }
  __shared__ float sS[4][64], sQ[4][64];
  sS[sub][c]=s; sQ[sub][c]=q;
  __syncthreads();
  if(sub==0){
    float a=0,bq=0;
    for(int i=0;i<4;i++){a+=sS[i][c]; bq+=sQ[i][c];}
    part[blockIdx.x*128+c*2]=a; part[blockIdx.x*128+c*2+1]=bq;
  }
}

__global__ void stg_bn_fin(const float* __restrict__ part, const float* __restrict__ g,
                           const float* __restrict__ b, float* __restrict__ stats){
  const int c=threadIdx.x; // 64 threads
  float s=0,q=0;
  for(int p=0;p<256;++p){ s+=part[p*128+c*2]; q+=part[p*128+c*2+1]; }
  const float invN=1.f/(float)NN;
  float mu=s*invN, var=q*invN-mu*mu;
  float istd=rsqrtf(var+1e-5f);
  float a=g[c]*istd;
  stats[c*2]=a; stats[c*2+1]=b[c]-mu*a;
}

__global__ __launch_bounds__(256)
void stg_bn_apply(const u16* __restrict__ in, const float* __restrict__ stats, u16* __restrict__ out){
  size_t idx=(size_t)blockIdx.x*256+threadIdx.x;
  int c=idx&63;
  float v=b2f(in[idx])*stats[c*2]+stats[c*2+1];
  out[idx]=f2b(fmaxf(v,0.f));
}

// ---------------- feats assembly ----------------
__global__ __launch_bounds__(256)
void stg_build_feats(const u16* __restrict__ h2, const float* __restrict__ x, u16* __restrict__ feats){
  size_t idx=(size_t)blockIdx.x*256+threadIdx.x;
  size_t row=idx/IN1P; int cc=(int)(idx%IN1P);
  u16 outv=0;
  if(cc<IN1){
    int k=cc/66, f=cc%66;
    size_t g=row/T_, t=row%T_;
    size_t node=g*NPER+t*K_+k;
    outv = (f<64)? h2[node*64+f] : f2b(x[node*2+(f-64)]);
  }
  feats[idx]=outv;
}

// ---------------- bf16 gemm-BT v5: generalized wave grid, single-barrier reg dbuf,
// col-fastest dispatch, plain C stores ----------------
template<int BM,int BN,int WR,int WC,int EPI>
__global__ __launch_bounds__(WR*WC*64)
void stg_gemm_bt(const u16* __restrict__ A, int ldA,
                 const u16* __restrict__ Bt, int ldB,
                 void* __restrict__ Cp, int ldC, int K,
                 const float* __restrict__ bias)
{
  constexpr int THREADS=WR*WC*64;
  constexpr int WM=BM/WR, WN=BN/WC, FM=WM/16, FN=WN/16;
  constexpr int QA=BM*4/THREADS, QB=BN*4/THREADS;
  __shared__ u16 As[2][BM*32];
  __shared__ u16 Bs[2][BN*32];
  const int tid=threadIdx.x, w=tid>>6, lane=tid&63;
  const int wr=w/WC, wc=w%WC;
  const size_t row0=(size_t)blockIdx.y*BM;   // rows on slow axis
  const size_t col0=(size_t)blockIdx.x*BN;   // cols on fast axis
  f32x4 acc[FM][FN];
  #pragma unroll
  for(int i=0;i<FM;i++)
    #pragma unroll
    for(int j=0;j<FN;j++)
      #pragma unroll
      for(int r=0;r<4;r++) acc[i][j][r]=0.f;

  // staging bijection: short8 slot s -> row=s>>2, colgrp=s&3, LDS byte off = s*16
  const u16* gA[QA]; const u16* gB[QB]; int lA_[QA], lB_[QB];
  #pragma unroll
  for(int q=0;q<QA;++q){
    const int s=tid+q*THREADS;
    gA[q]=A+(row0+(s>>2))*(size_t)ldA+(s&3)*8;
    lA_[q]=s*8;
  }
  #pragma unroll
  for(int q=0;q<QB;++q){
    const int s=tid+q*THREADS;
    gB[q]=Bt+(col0+(s>>2))*(size_t)ldB+(s&3)*8;
    lB_[q]=s*8;
  }

  short8 ra[QA], rb[QB];
  #pragma unroll
  for(int q=0;q<QA;++q) ra[q]=*(const short8*)(gA[q]);
  #pragma unroll
  for(int q=0;q<QB;++q) rb[q]=*(const short8*)(gB[q]);
  #pragma unroll
  for(int q=0;q<QA;++q) *(short8*)&As[0][lA_[q]]=ra[q];
  #pragma unroll
  for(int q=0;q<QB;++q) *(short8*)&Bs[0][lB_[q]]=rb[q];

  const int nIter=K/32;
  int cur=0;
  for(int it=0; it<nIter; ++it){
    if(it<nIter-1){
      #pragma unroll
      for(int q=0;q<QA;++q) ra[q]=*(const short8*)(gA[q]+(it+1)*32);
      #pragma unroll
      for(int q=0;q<QB;++q) rb[q]=*(const short8*)(gB[q]+(it+1)*32);
    }
    __syncthreads();                          // buf[cur] fully staged
    short8 af[FM], bf[FN];
    #pragma unroll
    for(int mi=0;mi<FM;mi++)
      af[mi]=*(const short8*)&As[cur][(wr*WM+mi*16+(lane&15))*32+(lane>>4)*8];
    #pragma unroll
    for(int ni=0;ni<FN;ni++)
      bf[ni]=*(const short8*)&Bs[cur][(wc*WN+ni*16+(lane&15))*32+(lane>>4)*8];
    #pragma unroll
    for(int mi=0;mi<FM;mi++)
      #pragma unroll
      for(int ni=0;ni<FN;ni++)
        acc[mi][ni]=__builtin_amdgcn_mfma_f32_16x16x32_bf16(af[mi],bf[ni],acc[mi][ni],0,0,0);
    if(it<nIter-1){
      #pragma unroll
      for(int q=0;q<QA;++q) *(short8*)&As[cur^1][lA_[q]]=ra[q];
      #pragma unroll
      for(int q=0;q<QB;++q) *(short8*)&Bs[cur^1][lB_[q]]=rb[q];
    }
    cur^=1;
  }
  #pragma unroll
  for(int mi=0;mi<FM;mi++)
   #pragma unroll
   for(int ni=0;ni<FN;ni++)
    #pragma unroll
    for(int r=0;r<4;r++){
      const size_t row=row0+wr*WM+mi*16+(lane>>4)*4+r;
      const size_t col=col0+wc*WN+ni*16+(lane&15);
      float v=acc[mi][ni][r];
      if constexpr (EPI==0){ ((u16*)Cp)[row*ldC+col]=f2b(v); }
      else if constexpr (EPI==1){ v+=bias[col]; ((u16*)Cp)[row*ldC+col]=f2b(fmaxf(v,0.f)); }
      else { if(col<OUT_){ ((float*)Cp)[row*ldC+col]=v+bias[col]; } }
    }
}

// ---------------- fused LSTM step v6: BK=128 (4 K-iters, 4 panels/buffer) ----------------
// grid (4, 32, 2): 64x64 tiles; 8 waves (2x4), wave tile 32x16. Same ascending-k MFMA
// order as v5 (bit-identical); halved barrier count, 2x loads in flight per window.
__global__ __launch_bounds__(512)
void stg_lstm_step(const u16* __restrict__ hprev, u16* __restrict__ hcur,
                   float* __restrict__ cst,
                   const u16* __restrict__ whh,       // [2][2048][512] permuted
                   const u16* __restrict__ xprAll,    // [23040][4096] (F|B halves)
                   const float* __restrict__ bias,    // [2][2048]
                   u16* __restrict__ seq,             // [23040][1024]
                   int t)
{
  __shared__ u16 As[2][4*2048];   // 2 buf x 4 panels x [64 rows][32 k] frag layout (32KB)
  __shared__ u16 Bs[2][4*2048];   // (32KB)
  __shared__ float Zs[64*64];     // (16KB)
  const int dir = blockIdx.z;
  const int tt  = dir ? (T_-1-t) : t;
  const u16* xp = xprAll + (size_t)dir*G4;
  const u16* Ap = hprev + (size_t)dir*B_*LH;
  const u16* Bp = whh   + (size_t)dir*G4*LH;
  const int tid=threadIdx.x, w=tid>>6, lane=tid&63;
  const int wr=w>>2, wc=w&3;                 // 2x4 wave grid; wave tile 32 rows x 16 cols
  const int row0=blockIdx.x*64, col0=blockIdx.y*64;

  // ---- T14 issue-early prefetches (consumed after the K-loop) ----
  const int gc_ = col0 + wc*16 + (lane&15);
  const float bias_v = bias[dir*G4 + gc_];
  u16 xpr_[2][4];
  #pragma unroll
  for(int mi=0;mi<2;mi++)
    #pragma unroll
    for(int r=0;r<4;r++){
      const int b=row0+wr*32+mi*16+(lane>>4)*4+r;
      xpr_[mi][r]=xp[(size_t)(b*T_+tt)*G8+gc_];
    }
  const int rlA=tid>>4,        uA=tid&15;
  const int rlB=(tid+512)>>4,  uB=tid&15;
  const size_t ciA=(size_t)dir*B_*LH + (size_t)(row0+rlA)*LH + (col0>>2)+uA;
  const size_t ciB=(size_t)dir*B_*LH + (size_t)(row0+rlB)*LH + (col0>>2)+uB;
  const float cprevA=cst[ciA];
  const float cprevB=cst[ciB];

  // staging: 2 slots/thread/matrix per iter; slot s=tid+j*512 in [0,1024):
  // panel=s>>8, srow=(s>>2)&63, scO=(s&3)*8 ; LDS byte off = s*16 (u16 idx s*8)
  const u16* gA[2]; const u16* gB[2]; int ls_[2];
  #pragma unroll
  for(int j=0;j<2;++j){
    const int s=tid+j*512;
    const int panel=s>>8, srow=(s>>2)&63, scO=(s&3)*8;
    gA[j]=Ap + (size_t)(row0+srow)*LH + panel*32 + scO;
    gB[j]=Bp + (size_t)(col0+srow)*LH + panel*32 + scO;
    ls_[j]=s*8;
  }

  f32x4 acc[2];
  #pragma unroll
  for(int i=0;i<2;i++)
    #pragma unroll
    for(int r=0;r<4;r++) acc[i][r]=0.f;

  short8 ra[2], rb[2];
  #pragma unroll
  for(int j=0;j<2;++j){ ra[j]=*(const short8*)(gA[j]); rb[j]=*(const short8*)(gB[j]); }
  #pragma unroll
  for(int j=0;j<2;++j){ *(short8*)&As[0][ls_[j]]=ra[j]; *(short8*)&Bs[0][ls_[j]]=rb[j]; }

  int cur=0;
  for(int it=0; it<4; ++it){
    if(it<3){
      #pragma unroll
      for(int j=0;j<2;++j){
        ra[j]=*(const short8*)(gA[j]+(it+1)*128);
        rb[j]=*(const short8*)(gB[j]+(it+1)*128);
      }
    }
    __syncthreads();                          // buf[cur] fully staged
    #pragma unroll
    for(int p=0;p<4;++p){
      short8 af[2], bf;
      #pragma unroll
      for(int mi=0;mi<2;mi++)
        af[mi]=*(const short8*)&As[cur][p*2048+(wr*32+mi*16+(lane&15))*32+(lane>>4)*8];
      bf=*(const short8*)&Bs[cur][p*2048+(wc*16+(lane&15))*32+(lane>>4)*8];
      #pragma unroll
      for(int mi=0;mi<2;mi++)
        acc[mi]=__builtin_amdgcn_mfma_f32_16x16x32_bf16(af[mi],bf,acc[mi],0,0,0);
    }
    if(it<3){
      #pragma unroll
      for(int j=0;j<2;++j){ *(short8*)&As[cur^1][ls_[j]]=ra[j]; *(short8*)&Bs[cur^1][ls_[j]]=rb[j]; }
    }
    cur^=1;
  }
  // z -> LDS (gates of a unit in 4 consecutive cols thanks to row permute)
  #pragma unroll
  for(int mi=0;mi<2;mi++)
    #pragma unroll
    for(int r=0;r<4;r++){
      const int rl=wr*32+mi*16+(lane>>4)*4+r;
      const int cl=wc*16+(lane&15);
      Zs[rl*64+cl]=acc[mi][r] + b2f(xpr_[mi][r]) + bias_v;
    }
  __syncthreads();
  // cell update: 1024 cells, 2 per thread (unrolled; cst prefetched)
  {
    const float zi=Zs[rlA*64+4*uA+0], zf=Zs[rlA*64+4*uA+1];
    const float zg=Zs[rlA*64+4*uA+2], zo=Zs[rlA*64+4*uA+3];
    float c = sigm(zf)*cprevA + sigm(zi)*tanh_(zg);
    cst[ciA]=c;
    float h = sigm(zo)*tanh_(c);
    hcur[ciA]=f2b(h);
    seq[(size_t)((row0+rlA)*T_+tt)*(2*LH) + (size_t)dir*LH + (col0>>2)+uA]=f2b(h);
  }
  {
    const float zi=Zs[rlB*64+4*uB+0], zf=Zs[rlB*64+4*uB+1];
    const float zg=Zs[rlB*64+4*uB+2], zo=Zs[rlB*64+4*uB+3];
    float c = sigm(zf)*cprevB + sigm(zi)*tanh_(zg);
    cst[ciB]=c;
    float h = sigm(zo)*tanh_(c);
    hcur[ciB]=f2b(h);
    seq[(size_t)((row0+rlB)*T_+tt)*(2*LH) + (size_t)dir*LH + (col0>>2)+uB]=f2b(h);
  }
}

// ---------------- host ----------------
extern "C" void kernel_launch(void* const* d_in, const int* in_sizes, int n_in,
                              void* d_out, int out_size, void* d_ws, size_t ws_size,
                              hipStream_t stream)
{
  (void)in_sizes; (void)n_in;
  const float* x    =(const float*)d_in[0];
  const float* g1W  =(const float*)d_in[2];
  const float* g1as =(const float*)d_in[3];
  const float* g1ad =(const float*)d_in[4];
  const float* g1b  =(const float*)d_in[5];
  const float* bn1g =(const float*)d_in[6];
  const float* bn1b =(const float*)d_in[7];
  const float* g2W  =(const float*)d_in[8];
  const float* g2as =(const float*)d_in[9];
  const float* g2ad =(const float*)d_in[10];
  const float* g2b  =(const float*)d_in[11];
  const float* bn2g =(const float*)d_in[12];
  const float* bn2b =(const float*)d_in[13];
  const float* l1f_wih=(const float*)d_in[14];
  const float* l1f_whh=(const float*)d_in[15];
  const float* l1f_bih=(const float*)d_in[16];
  const float* l1f_bhh=(const float*)d_in[17];
  const float* l1b_wih=(const float*)d_in[18];
  const float* l1b_whh=(const float*)d_in[19];
  const float* l1b_bih=(const float*)d_in[20];
  const float* l1b_bhh=(const float*)d_in[21];
  const float* l2f_wih=(const float*)d_in[22];
  const float* l2f_whh=(const float*)d_in[23];
  const float* l2f_bih=(const float*)d_in[24];
  const float* l2f_bhh=(const float*)d_in[25];
  const float* l2b_wih=(const float*)d_in[26];
  const float* l2b_whh=(const float*)d_in[27];
  const float* l2b_bih=(const float*)d_in[28];
  const float* l2b_bhh=(const float*)d_in[29];
  const float* h1w  =(const float*)d_in[30];
  const float* h1b  =(const float*)d_in[31];
  const float* h2w  =(const float*)d_in[32];
  const float* h2b  =(const float*)d_in[33];

  // ---------- workspace layout with phase-based aliasing ----------
  const size_t SZ_w1ih  = (size_t)G4*IN1P*2;
  const size_t SZ_w2ih  = (size_t)G4*1024*2;
  const size_t SZ_whh   = (size_t)4*G4*LH*2;
  const size_t SZ_bias  = (size_t)4*G4*4;
  const size_t SZ_w2gT  = (size_t)64*64*2;
  const size_t SZ_h1T   = (size_t)256*1024*2;
  const size_t SZ_h2T   = (size_t)64*256*2;
  const size_t SZ_part  = (size_t)256*128*4;
  const size_t SZ_stats = (size_t)64*2*4;
  const size_t SZ_hs    = (size_t)2*B_*LH*2;
  const size_t SZ_cs    = (size_t)2*B_*LH*4;
  const size_t SZ_xprA  = (size_t)SEQR*G8*2;        // merged [23040][4096]
  const size_t SZ_feats = (size_t)SEQR*IN1P*2;
  const size_t SZ_gat   = (size_t)NN*64*2;
  const size_t SZ_sc    = (size_t)NN*4;

  char* base=(char*)d_ws; size_t o=0;
  auto take=[&](size_t b)->size_t{ size_t r=o; o=(o+b+255)&~(size_t)255; return r; };
  const size_t off_w1ih = take(2*SZ_w1ih);
  const size_t off_whh  = take(SZ_whh);
  const size_t off_bias = take(SZ_bias);
  const size_t off_w2gT = take(SZ_w2gT);
  const size_t off_h1T  = take(SZ_h1T);
  const size_t off_h2T  = take(SZ_h2T);
  const size_t off_part = take(SZ_part);
  const size_t off_stat = take(SZ_stats);
  const size_t off_hs0  = take(SZ_hs);
  const size_t off_hs1  = take(SZ_hs);
  const size_t off_cs   = take(SZ_cs);
  const size_t off_R12  = take(SZ_xprA);
  const size_t off_R3   = take(SZ_feats);
  const size_t NEED = o;
  if (NEED > ws_size) {
    stg_sentinel<<<(out_size+255)/256,256,0,stream>>>((float*)d_out, out_size);
    return;
  }

  u16* w1ihF=(u16*)(base+off_w1ih);              // [w1ihF|w1ihB] contiguous = [4096][1152]
  u16* w1ihB=(u16*)(base+off_w1ih+SZ_w1ih);
  u16* w2ihF=(u16*)(base+off_w1ih);              // alias after L1 proj: [4096][1024]
  u16* w2ihB=(u16*)(base+off_w1ih+SZ_w2ih);
  u16* whhAll=(u16*)(base+off_whh);
  float* biasAll=(float*)(base+off_bias);
  u16* w2gT=(u16*)(base+off_w2gT);
  u16* h1T =(u16*)(base+off_h1T);
  u16* h2T =(u16*)(base+off_h2T);
  float* part=(float*)(base+off_part);
  float* stats=(float*)(base+off_stat);
  u16* hs0=(u16*)(base+off_hs0);
  u16* hs1=(u16*)(base+off_hs1);
  float* cs=(float*)(base+off_cs);
  u16* xprAll=(u16*)(base+off_R12);              // merged [23040][4096]
  u16* xpB_=(u16*)(base+off_R12);                // GAT-phase aliases within R12
  u16* aggB=(u16*)(base+off_R12+SZ_gat);
  u16* hB  =(u16*)(base+off_R12+2*SZ_gat);
  float* ssrc=(float*)(base+off_R12+3*SZ_gat);
  float* sdst=(float*)(base+off_R12+3*SZ_gat+SZ_sc);
  u16* mid =(u16*)(base+off_R12);                // head phase: xpr dead
  u16* feats=(u16*)(base+off_R3);
  u16* seq  =(u16*)(base+off_R3);

  // ---- prep ----
  stg_permute_w<<<G4*IN1P/256,256,0,stream>>>(l1f_wih,w1ihF,IN1,IN1P);
  stg_permute_w<<<G4*IN1P/256,256,0,stream>>>(l1b_wih,w1ihB,IN1,IN1P);
  stg_permute_w<<<G4*LH/256,256,0,stream>>>(l1f_whh,whhAll+0*(size_t)G4*LH,LH,LH);
  stg_permute_w<<<G4*LH/256,256,0,stream>>>(l1b_whh,whhAll+1*(size_t)G4*LH,LH,LH);
  stg_permute_w<<<G4*LH/256,256,0,stream>>>(l2f_whh,whhAll+2*(size_t)G4*LH,LH,LH);
  stg_permute_w<<<G4*LH/256,256,0,stream>>>(l2b_whh,whhAll+3*(size_t)G4*LH,LH,LH);
  stg_prep_bias<<<G4/256,256,0,stream>>>(l1f_bih,l1f_bhh,biasAll+0*G4);
  stg_prep_bias<<<G4/256,256,0,stream>>>(l1b_bih,l1b_bhh,biasAll+1*G4);
  stg_prep_bias<<<G4/256,256,0,stream>>>(l2f_bih,l2f_bhh,biasAll+2*G4);
  stg_prep_bias<<<G4/256,256,0,stream>>>(l2b_bih,l2b_bhh,biasAll+3*G4);
  stg_transpose_pad<<<64*64/256,256,0,stream>>>(g2W,w2gT,64,64,64);
  stg_transpose_pad<<<256*1024/256,256,0,stream>>>(h1w,h1T,1024,256,256);
  stg_transpose_pad<<<64*256/256,256,0,stream>>>(h2w,h2T,256,57,64);

  // ---- GAT layer 1 (scores fused into xp) ----
  stg_gat1_xp<<<NN*64/256,256,0,stream>>>(x,g1W,xpB_,g1as,g1ad,ssrc,sdst);
  stg_gat_agg<<<NN/4,256,0,stream>>>(xpB_,ssrc,sdst,g1b,aggB);
  stg_bn_part<<<256,256,0,stream>>>(aggB,part);
  stg_bn_fin<<<1,64,0,stream>>>(part,bn1g,bn1b,stats);
  stg_bn_apply<<<NN*64/256,256,0,stream>>>(aggB,stats,hB);

  // ---- GAT layer 2 ----
  stg_gemm_bt<128,64,2,2,0><<<dim3(1,NN/128),256,0,stream>>>(hB,64,w2gT,64,xpB_,64,64,nullptr);
  stg_scores<<<NN/4,256,0,stream>>>(xpB_,g2as,g2ad,ssrc,sdst);
  stg_gat_agg<<<NN/4,256,0,stream>>>(xpB_,ssrc,sdst,g2b,aggB);
  stg_bn_part<<<256,256,0,stream>>>(aggB,part);
  stg_bn_fin<<<1,64,0,stream>>>(part,bn2g,bn2b,stats);
  stg_bn_apply<<<NN*64/256,256,0,stream>>>(aggB,stats,hB);

  // ---- feats ----
  stg_build_feats<<<SEQR*IN1P/256,256,0,stream>>>(hB,x,feats);

  // ---- BiLSTM layer 1 projection: ONE merged 128x256 GEMM (8 waves) ----
  stg_gemm_bt<128,256,2,4,0><<<dim3(G8/256,SEQR/128),512,0,stream>>>(feats,IN1P,w1ihF,IN1P,xprAll,G8,IN1P,nullptr);
  stg_permute_w<<<G4*1024/256,256,0,stream>>>(l2f_wih,w2ihF,1024,1024);
  stg_permute_w<<<G4*1024/256,256,0,stream>>>(l2b_wih,w2ihB,1024,1024);

  hipMemsetAsync(hs0,0,SZ_hs,stream);
  hipMemsetAsync(cs,0,SZ_cs,stream);
  for(int t=0;t<T_;++t){
    u16* hp=(t&1)?hs1:hs0; u16* hc=(t&1)?hs0:hs1;
    stg_lstm_step<<<dim3(B_/64,G4/64,2),512,0,stream>>>(hp,hc,cs,whhAll,xprAll,biasAll,seq,t);
  }

  // ---- BiLSTM layer 2: merged projection ----
  stg_gemm_bt<128,256,2,4,0><<<dim3(G8/256,SEQR/128),512,0,stream>>>(seq,1024,w2ihF,1024,xprAll,G8,1024,nullptr);
  hipMemsetAsync(hs0,0,SZ_hs,stream);
  hipMemsetAsync(cs,0,SZ_cs,stream);
  for(int t=0;t<T_;++t){
    u16* hp=(t&1)?hs1:hs0; u16* hc=(t&1)?hs0:hs1;
    stg_lstm_step<<<dim3(B_/64,G4/64,2),512,0,stream>>>(hp,hc,cs,whhAll+(size_t)2*G4*LH,xprAll,biasAll+2*G4,seq,t);
  }

  // ---- heads ----
  stg_gemm_bt<128,128,2,2,1><<<dim3(256/128,SEQR/128),256,0,stream>>>(seq,1024,h1T,1024,mid,256,1024,h1b);
  stg_gemm_bt<128,64,2,2,2><<<dim3(1,SEQR/128),256,0,stream>>>(mid,256,h2T,256,d_out,OUT_,256,h2b);
}

// Round 17
// 2339.241 us; speedup vs baseline: 1.0399x; 1.0399x over previous
//
#include <hip/hip_runtime.h>
#include <cstdint>
#include <cstddef>

// ---------------- model constants ----------------
#define B_    256
#define T_    90
#define K_    17
#define NPER  1530              // T_*K_
#define NN    (B_*NPER)         // 391680 nodes
#define H_    64
#define LH    512
#define G4    2048              // 4*LH
#define G8    4096              // both directions
#define IN1   1122              // K_*(H_+2)
#define IN1P  1152              // padded to mult of 32
#define SEQR  (B_*T_)           // 23040
#define OUT_  57

typedef unsigned short u16;
typedef __attribute__((ext_vector_type(8))) short short8;
typedef __attribute__((ext_vector_type(4))) float f32x4;

__device__ __forceinline__ float b2f(u16 u){ union{unsigned i; float f;} x; x.i=((unsigned)u)<<16; return x.f; }
__device__ __forceinline__ u16 f2b(float f){ union{float f; unsigned i;} x; x.f=f; unsigned r=x.i+0x7fffu+((x.i>>16)&1u); return (u16)(r>>16); }
__device__ __forceinline__ float sigm(float v){ return 1.f/(1.f+__expf(-v)); }
__device__ __forceinline__ float tanh_(float v){ return 2.f*sigm(2.f*v)-1.f; }

// ---------------- diagnostic sentinel (ws too small) ----------------
__global__ __launch_bounds__(256)
void stg_sentinel(float* __restrict__ out, int n){
  int i=blockIdx.x*256+threadIdx.x;
  if(i<n) out[i]=123.0f;
}

// ---------------- prep kernels ----------------
__global__ __launch_bounds__(256)
void stg_permute_w(const float* __restrict__ src, u16* __restrict__ dst, int Ks, int Kd){
  size_t idx=(size_t)blockIdx.x*256+threadIdx.x;
  int rn=(int)(idx/Kd), kk=(int)(idx%Kd);
  int j=rn>>2, G=rn&3, ro=G*LH+j;
  dst[idx] = (kk<Ks)? f2b(src[(size_t)ro*Ks+kk]) : (u16)0;
}

__global__ __launch_bounds__(256)
void stg_prep_bias(const float* __restrict__ bih, const float* __restrict__ bhh, float* __restrict__ dst){
  int rn=blockIdx.x*256+threadIdx.x;
  int j=rn>>2, G=rn&3, ro=G*LH+j;
  dst[rn]=bih[ro]+bhh[ro];
}

__global__ __launch_bounds__(256)
void stg_transpose_pad(const float* __restrict__ src, u16* __restrict__ dst, int R, int C, int Crows){
  size_t idx=(size_t)blockIdx.x*256+threadIdx.x;
  int c=(int)(idx/R), r=(int)(idx%R);
  dst[idx] = (c<C)? f2b(src[(size_t)r*C+c]) : (u16)0;
  (void)Crows;
}

// ---------------- GAT ----------------
// xp + fused attention scores (wave == node, lane == channel)
__global__ __launch_bounds__(256)
void stg_gat1_xp(const float* __restrict__ x, const float* __restrict__ W, u16* __restrict__ xp,
                 const float* __restrict__ as, const float* __restrict__ ad,
                 float* __restrict__ ssrc, float* __restrict__ sdst){
  size_t idx=(size_t)blockIdx.x*256+threadIdx.x;
  size_t n=idx>>6; int c=idx&63;
  float v=x[n*2]*W[c]+x[n*2+1]*W[64+c];
  u16 vb16=f2b(v);
  xp[idx]=vb16;
  float vb=b2f(vb16);
  float s1=vb*as[c], s2=vb*ad[c];
  #pragma unroll
  for(int m=1;m<64;m<<=1){ s1+=__shfl_xor(s1,m); s2+=__shfl_xor(s2,m); }
  if(c==0){ ssrc[n]=s1; sdst[n]=s2; }
}

__global__ __launch_bounds__(256)
void stg_scores(const u16* __restrict__ xp, const float* __restrict__ as, const float* __restrict__ ad,
                float* __restrict__ ssrc, float* __restrict__ sdst){
  const int lane=threadIdx.x&63;
  const size_t n=(size_t)blockIdx.x*4+(threadIdx.x>>6);
  float v=b2f(xp[n*64+lane]);
  float s1=v*as[lane], s2=v*ad[lane];
  #pragma unroll
  for(int m=1;m<64;m<<=1){ s1+=__shfl_xor(s1,m); s2+=__shfl_xor(s2,m); }
  if(lane==0){ ssrc[n]=s1; sdst[n]=s2; }
}

// skeleton adjacency derived from CONNS (undirected)
__constant__ int c_deg[17]={2,3,3,2,2,4,4,2,2,1,1,3,3,2,2,1,1};
__constant__ int c_adj[17][4]={{1,2,0,0},{2,0,3,0},{1,0,4,0},{1,5,0,0},{2,6,0,0},
 {11,6,7,3},{12,5,8,4},{5,9,0,0},{6,10,0,0},{7,0,0,0},{8,0,0,0},
 {13,12,5,0},{14,11,6,0},{15,11,0,0},{16,12,0,0},{13,0,0,0},{14,0,0,0}};

// wave per dst node; lane = channel. FULLY UNROLLED 7 slots, all regs (no scratch).
__global__ __launch_bounds__(256)
void stg_gat_agg(const u16* __restrict__ xp, const float* __restrict__ ssrc, const float* __restrict__ sdst,
                 const float* __restrict__ bias, u16* __restrict__ out){
  const int lane=threadIdx.x&63;
  const int n=blockIdx.x*4+(threadIdx.x>>6);
  const int r=n%NPER, t=r/K_, k=r%K_;
  const int dg=c_deg[k];
  const int base=n-k;
  const int nb0=n;
  const int nb1=(t>0)?      n-K_ : n;  const bool v1=(t>0);
  const int nb2=(t<T_-1)?   n+K_ : n;  const bool v2=(t<T_-1);
  const int nb3=base+c_adj[k][0];
  const int nb4=base+c_adj[k][1];      const bool v4=(dg>1);
  const int nb5=base+c_adj[k][2];      const bool v5=(dg>2);
  const int nb6=base+c_adj[k][3];      const bool v6=(dg>3);
  const float sd=sdst[n];
  const float NEG=-1e30f;
  auto lrelu=[](float v){ return v>0.f? v : 0.2f*v; };
  float e0=lrelu(ssrc[nb0]+sd);
  float e1=v1? lrelu(ssrc[nb1]+sd) : NEG;
  float e2=v2? lrelu(ssrc[nb2]+sd) : NEG;
  float e3=    lrelu(ssrc[nb3]+sd);
  float e4=v4? lrelu(ssrc[nb4]+sd) : NEG;
  float e5=v5? lrelu(ssrc[nb5]+sd) : NEG;
  float e6=v6? lrelu(ssrc[nb6]+sd) : NEG;
  float mx=fmaxf(fmaxf(fmaxf(e0,e1),fmaxf(e2,e3)),fmaxf(fmaxf(e4,e5),e6));
  float w0=__expf(e0-mx), w1=__expf(e1-mx), w2=__expf(e2-mx), w3=__expf(e3-mx);
  float w4=__expf(e4-mx), w5=__expf(e5-mx), w6=__expf(e6-mx);
  const float inv=1.f/(w0+w1+w2+w3+w4+w5+w6);
  float acc = w0*b2f(xp[(size_t)nb0*64+lane])
            + w1*b2f(xp[(size_t)nb1*64+lane])
            + w2*b2f(xp[(size_t)nb2*64+lane])
            + w3*b2f(xp[(size_t)nb3*64+lane])
            + w4*b2f(xp[(size_t)nb4*64+lane])
            + w5*b2f(xp[(size_t)nb5*64+lane])
            + w6*b2f(xp[(size_t)nb6*64+lane]);
  out[(size_t)n*64+lane]=f2b(acc*inv+bias[lane]);
}

// ---------------- batch norm (deterministic 2-stage) ----------------
__global__ __launch_bounds__(256)
void stg_bn_part(const u16* __restrict__ in, float* __restrict__ part){
  const int c=threadIdx.x&63, sub=threadIdx.x>>6;
  float s=0.f,q=0.f;
  for(size_t n=(size_t)blockIdx.x*4+sub; n<NN; n+=1024){
    float v=b2f(in[n*64+c]); s+=v; q+=v*v;
  }
  __shared__ float sS[4][64], sQ[4][64];
  sS[sub][c]=s; sQ[sub][c]=q;
  __syncthreads();
  if(sub==0){
    float a=0,bq=0;
    for(int i=0;i<4;i++){a+=sS[i][c]; bq+=sQ[i][c];}
    part[blockIdx.x*128+c*2]=a; part[blockIdx.x*128+c*2+1]=bq;
  }
}

__global__ void stg_bn_fin(const float* __restrict__ part, const float* __restrict__ g,
                           const float* __restrict__ b, float* __restrict__ stats){
  const int c=threadIdx.x; // 64 threads
  float s=0,q=0;
  for(int p=0;p<256;++p){ s+=part[p*128+c*2]; q+=part[p*128+c*2+1]; }
  const float invN=1.f/(float)NN;
  float mu=s*invN, var=q*invN-mu*mu;
  float istd=rsqrtf(var+1e-5f);
  float a=g[c]*istd;
  stats[c*2]=a; stats[c*2+1]=b[c]-mu*a;
}

__global__ __launch_bounds__(256)
void stg_bn_apply(const u16* __restrict__ in, const float* __restrict__ stats, u16* __restrict__ out){
  size_t idx=(size_t)blockIdx.x*256+threadIdx.x;
  int c=idx&63;
  float v=b2f(in[idx])*stats[c*2]+stats[c*2+1];
  out[idx]=f2b(fmaxf(v,0.f));
}

// ---------------- feats assembly ----------------
__global__ __launch_bounds__(256)
void stg_build_feats(const u16* __restrict__ h2, const float* __restrict__ x, u16* __restrict__ feats){
  size_t idx=(size_t)blockIdx.x*256+threadIdx.x;
  size_t row=idx/IN1P; int cc=(int)(idx%IN1P);
  u16 outv=0;
  if(cc<IN1){
    int k=cc/66, f=cc%66;
    size_t g=row/T_, t=row%T_;
    size_t node=g*NPER+t*K_+k;
    outv = (f<64)? h2[node*64+f] : f2b(x[node*2+(f-64)]);
  }
  feats[idx]=outv;
}

// ---------------- bf16 gemm-BT v5: generalized wave grid, single-barrier reg dbuf,
// col-fastest dispatch, plain C stores ----------------
template<int BM,int BN,int WR,int WC,int EPI>
__global__ __launch_bounds__(WR*WC*64)
void stg_gemm_bt(const u16* __restrict__ A, int ldA,
                 const u16* __restrict__ Bt, int ldB,
                 void* __restrict__ Cp, int ldC, int K,
                 const float* __restrict__ bias)
{
  constexpr int THREADS=WR*WC*64;
  constexpr int WM=BM/WR, WN=BN/WC, FM=WM/16, FN=WN/16;
  constexpr int QA=BM*4/THREADS, QB=BN*4/THREADS;
  __shared__ u16 As[2][BM*32];
  __shared__ u16 Bs[2][BN*32];
  const int tid=threadIdx.x, w=tid>>6, lane=tid&63;
  const int wr=w/WC, wc=w%WC;
  const size_t row0=(size_t)blockIdx.y*BM;   // rows on slow axis
  const size_t col0=(size_t)blockIdx.x*BN;   // cols on fast axis
  f32x4 acc[FM][FN];
  #pragma unroll
  for(int i=0;i<FM;i++)
    #pragma unroll
    for(int j=0;j<FN;j++)
      #pragma unroll
      for(int r=0;r<4;r++) acc[i][j][r]=0.f;

  // staging bijection: short8 slot s -> row=s>>2, colgrp=s&3, LDS byte off = s*16
  const u16* gA[QA]; const u16* gB[QB]; int lA_[QA], lB_[QB];
  #pragma unroll
  for(int q=0;q<QA;++q){
    const int s=tid+q*THREADS;
    gA[q]=A+(row0+(s>>2))*(size_t)ldA+(s&3)*8;
    lA_[q]=s*8;
  }
  #pragma unroll
  for(int q=0;q<QB;++q){
    const int s=tid+q*THREADS;
    gB[q]=Bt+(col0+(s>>2))*(size_t)ldB+(s&3)*8;
    lB_[q]=s*8;
  }

  short8 ra[QA], rb[QB];
  #pragma unroll
  for(int q=0;q<QA;++q) ra[q]=*(const short8*)(gA[q]);
  #pragma unroll
  for(int q=0;q<QB;++q) rb[q]=*(const short8*)(gB[q]);
  #pragma unroll
  for(int q=0;q<QA;++q) *(short8*)&As[0][lA_[q]]=ra[q];
  #pragma unroll
  for(int q=0;q<QB;++q) *(short8*)&Bs[0][lB_[q]]=rb[q];

  const int nIter=K/32;
  int cur=0;
  for(int it=0; it<nIter; ++it){
    if(it<nIter-1){
      #pragma unroll
      for(int q=0;q<QA;++q) ra[q]=*(const short8*)(gA[q]+(it+1)*32);
      #pragma unroll
      for(int q=0;q<QB;++q) rb[q]=*(const short8*)(gB[q]+(it+1)*32);
    }
    __syncthreads();                          // buf[cur] fully staged
    short8 af[FM], bf[FN];
    #pragma unroll
    for(int mi=0;mi<FM;mi++)
      af[mi]=*(const short8*)&As[cur][(wr*WM+mi*16+(lane&15))*32+(lane>>4)*8];
    #pragma unroll
    for(int ni=0;ni<FN;ni++)
      bf[ni]=*(const short8*)&Bs[cur][(wc*WN+ni*16+(lane&15))*32+(lane>>4)*8];
    #pragma unroll
    for(int mi=0;mi<FM;mi++)
      #pragma unroll
      for(int ni=0;ni<FN;ni++)
        acc[mi][ni]=__builtin_amdgcn_mfma_f32_16x16x32_bf16(af[mi],bf[ni],acc[mi][ni],0,0,0);
    if(it<nIter-1){
      #pragma unroll
      for(int q=0;q<QA;++q) *(short8*)&As[cur^1][lA_[q]]=ra[q];
      #pragma unroll
      for(int q=0;q<QB;++q) *(short8*)&Bs[cur^1][lB_[q]]=rb[q];
    }
    cur^=1;
  }
  #pragma unroll
  for(int mi=0;mi<FM;mi++)
   #pragma unroll
   for(int ni=0;ni<FN;ni++)
    #pragma unroll
    for(int r=0;r<4;r++){
      const size_t row=row0+wr*WM+mi*16+(lane>>4)*4+r;
      const size_t col=col0+wc*WN+ni*16+(lane&15);
      float v=acc[mi][ni][r];
      if constexpr (EPI==0){ ((u16*)Cp)[row*ldC+col]=f2b(v); }
      else if constexpr (EPI==1){ v+=bias[col]; ((u16*)Cp)[row*ldC+col]=f2b(fmaxf(v,0.f)); }
      else { if(col<OUT_){ ((float*)Cp)[row*ldC+col]=v+bias[col]; } }
    }
}

// ---------------- fused LSTM step v5b (measured best ~7.7us/step): BK=64, 8 iters ----------------
// grid (4, 32, 2): 64x64 tiles; 8 waves (2x4), wave tile 32x16. v2 K-loop + T14 prefetch.
__global__ __launch_bounds__(512)
void stg_lstm_step(const u16* __restrict__ hprev, u16* __restrict__ hcur,
                   float* __restrict__ cst,
                   const u16* __restrict__ whh,       // [2][2048][512] permuted
                   const u16* __restrict__ xprAll,    // [23040][4096] (F|B halves)
                   const float* __restrict__ bias,    // [2][2048]
                   u16* __restrict__ seq,             // [23040][1024]
                   int t)
{
  __shared__ u16 As[2][2*2048];
  __shared__ u16 Bs[2][2*2048];
  __shared__ float Zs[64*64];
  const int dir = blockIdx.z;
  const int tt  = dir ? (T_-1-t) : t;
  const u16* xp = xprAll + (size_t)dir*G4;
  const u16* Ap = hprev + (size_t)dir*B_*LH;
  const u16* Bp = whh   + (size_t)dir*G4*LH;
  const int tid=threadIdx.x, w=tid>>6, lane=tid&63;
  const int wr=w>>2, wc=w&3;                 // 2x4 wave grid; wave tile 32 rows x 16 cols
  const int row0=blockIdx.x*64, col0=blockIdx.y*64;

  // ---- T14 issue-early prefetches (consumed after the K-loop) ----
  const int gc_ = col0 + wc*16 + (lane&15);
  const float bias_v = bias[dir*G4 + gc_];
  u16 xpr_[2][4];
  #pragma unroll
  for(int mi=0;mi<2;mi++)
    #pragma unroll
    for(int r=0;r<4;r++){
      const int b=row0+wr*32+mi*16+(lane>>4)*4+r;
      xpr_[mi][r]=xp[(size_t)(b*T_+tt)*G8+gc_];
    }
  const int rlA=tid>>4,        uA=tid&15;
  const int rlB=(tid+512)>>4,  uB=tid&15;
  const size_t ciA=(size_t)dir*B_*LH + (size_t)(row0+rlA)*LH + (col0>>2)+uA;
  const size_t ciB=(size_t)dir*B_*LH + (size_t)(row0+rlB)*LH + (col0>>2)+uB;
  const float cprevA=cst[ciA];
  const float cprevB=cst[ciB];

  // staging map: one short8 of A + one of B per thread per tile
  const int sp=w>>2, ss=w&3;                 // panel(0/1), 16-row subtile(0..3)
  const int srow=ss*16+(lane>>2);
  const int scO=(lane&3)*8;
  const u16* gA = Ap + (size_t)(row0+srow)*LH + sp*32 + scO;
  const u16* gB = Bp + (size_t)(col0+srow)*LH + sp*32 + scO;
  const int lA = sp*2048 + srow*32 + scO;    // same layout for A and B

  f32x4 acc[2];
  #pragma unroll
  for(int i=0;i<2;i++)
    #pragma unroll
    for(int r=0;r<4;r++) acc[i][r]=0.f;

  short8 ra=*(const short8*)(gA);
  short8 rb=*(const short8*)(gB);
  *(short8*)&As[0][lA]=ra; *(short8*)&Bs[0][lA]=rb;

  int cur=0;
  for(int it=0; it<8; ++it){
    if(it<7){ ra=*(const short8*)(gA+(it+1)*64); rb=*(const short8*)(gB+(it+1)*64); }
    __syncthreads();                          // buf[cur] fully staged
    #pragma unroll
    for(int p=0;p<2;++p){
      short8 af[2], bf;
      #pragma unroll
      for(int mi=0;mi<2;mi++)
        af[mi]=*(const short8*)&As[cur][p*2048+(wr*32+mi*16+(lane&15))*32+(lane>>4)*8];
      bf=*(const short8*)&Bs[cur][p*2048+(wc*16+(lane&15))*32+(lane>>4)*8];
      #pragma unroll
      for(int mi=0;mi<2;mi++)
        acc[mi]=__builtin_amdgcn_mfma_f32_16x16x32_bf16(af[mi],bf,acc[mi],0,0,0);
    }
    if(it<7){ *(short8*)&As[cur^1][lA]=ra; *(short8*)&Bs[cur^1][lA]=rb; }
    cur^=1;
  }
  // z -> LDS (gates of a unit in 4 consecutive cols thanks to row permute)
  #pragma unroll
  for(int mi=0;mi<2;mi++)
    #pragma unroll
    for(int r=0;r<4;r++){
      const int rl=wr*32+mi*16+(lane>>4)*4+r;
      const int cl=wc*16+(lane&15);
      Zs[rl*64+cl]=acc[mi][r] + b2f(xpr_[mi][r]) + bias_v;
    }
  __syncthreads();
  // cell update: 1024 cells, 2 per thread (unrolled; cst prefetched)
  {
    const float zi=Zs[rlA*64+4*uA+0], zf=Zs[rlA*64+4*uA+1];
    const float zg=Zs[rlA*64+4*uA+2], zo=Zs[rlA*64+4*uA+3];
    float c = sigm(zf)*cprevA + sigm(zi)*tanh_(zg);
    cst[ciA]=c;
    float h = sigm(zo)*tanh_(c);
    hcur[ciA]=f2b(h);
    seq[(size_t)((row0+rlA)*T_+tt)*(2*LH) + (size_t)dir*LH + (col0>>2)+uA]=f2b(h);
  }
  {
    const float zi=Zs[rlB*64+4*uB+0], zf=Zs[rlB*64+4*uB+1];
    const float zg=Zs[rlB*64+4*uB+2], zo=Zs[rlB*64+4*uB+3];
    float c = sigm(zf)*cprevB + sigm(zi)*tanh_(zg);
    cst[ciB]=c;
    float h = sigm(zo)*tanh_(c);
    hcur[ciB]=f2b(h);
    seq[(size_t)((row0+rlB)*T_+tt)*(2*LH) + (size_t)dir*LH + (col0>>2)+uB]=f2b(h);
  }
}

// ---------------- host ----------------
extern "C" void kernel_launch(void* const* d_in, const int* in_sizes, int n_in,
                              void* d_out, int out_size, void* d_ws, size_t ws_size,
                              hipStream_t stream)
{
  (void)in_sizes; (void)n_in;
  const float* x    =(const float*)d_in[0];
  const float* g1W  =(const float*)d_in[2];
  const float* g1as =(const float*)d_in[3];
  const float* g1ad =(const float*)d_in[4];
  const float* g1b  =(const float*)d_in[5];
  const float* bn1g =(const float*)d_in[6];
  const float* bn1b =(const float*)d_in[7];
  const float* g2W  =(const float*)d_in[8];
  const float* g2as =(const float*)d_in[9];
  const float* g2ad =(const float*)d_in[10];
  const float* g2b  =(const float*)d_in[11];
  const float* bn2g =(const float*)d_in[12];
  const float* bn2b =(const float*)d_in[13];
  const float* l1f_wih=(const float*)d_in[14];
  const float* l1f_whh=(const float*)d_in[15];
  const float* l1f_bih=(const float*)d_in[16];
  const float* l1f_bhh=(const float*)d_in[17];
  const float* l1b_wih=(const float*)d_in[18];
  const float* l1b_whh=(const float*)d_in[19];
  const float* l1b_bih=(const float*)d_in[20];
  const float* l1b_bhh=(const float*)d_in[21];
  const float* l2f_wih=(const float*)d_in[22];
  const float* l2f_whh=(const float*)d_in[23];
  const float* l2f_bih=(const float*)d_in[24];
  const float* l2f_bhh=(const float*)d_in[25];
  const float* l2b_wih=(const float*)d_in[26];
  const float* l2b_whh=(const float*)d_in[27];
  const float* l2b_bih=(const float*)d_in[28];
  const float* l2b_bhh=(const float*)d_in[29];
  const float* h1w  =(const float*)d_in[30];
  const float* h1b  =(const float*)d_in[31];
  const float* h2w  =(const float*)d_in[32];
  const float* h2b  =(const float*)d_in[33];

  // ---------- workspace layout with phase-based aliasing ----------
  const size_t SZ_w1ih  = (size_t)G4*IN1P*2;
  const size_t SZ_w2ih  = (size_t)G4*1024*2;
  const size_t SZ_whh   = (size_t)4*G4*LH*2;
  const size_t SZ_bias  = (size_t)4*G4*4;
  const size_t SZ_w2gT  = (size_t)64*64*2;
  const size_t SZ_h1T   = (size_t)256*1024*2;
  const size_t SZ_h2T   = (size_t)64*256*2;
  const size_t SZ_part  = (size_t)256*128*4;
  const size_t SZ_stats = (size_t)64*2*4;
  const size_t SZ_hs    = (size_t)2*B_*LH*2;
  const size_t SZ_cs    = (size_t)2*B_*LH*4;
  const size_t SZ_xprA  = (size_t)SEQR*G8*2;        // merged [23040][4096]
  const size_t SZ_feats = (size_t)SEQR*IN1P*2;
  const size_t SZ_gat   = (size_t)NN*64*2;
  const size_t SZ_sc    = (size_t)NN*4;

  char* base=(char*)d_ws; size_t o=0;
  auto take=[&](size_t b)->size_t{ size_t r=o; o=(o+b+255)&~(size_t)255; return r; };
  const size_t off_w1ih = take(2*SZ_w1ih);
  const size_t off_whh  = take(SZ_whh);
  const size_t off_bias = take(SZ_bias);
  const size_t off_w2gT = take(SZ_w2gT);
  const size_t off_h1T  = take(SZ_h1T);
  const size_t off_h2T  = take(SZ_h2T);
  const size_t off_part = take(SZ_part);
  const size_t off_stat = take(SZ_stats);
  const size_t off_hs0  = take(SZ_hs);
  const size_t off_hs1  = take(SZ_hs);
  const size_t off_cs   = take(SZ_cs);
  const size_t off_R12  = take(SZ_xprA);
  const size_t off_R3   = take(SZ_feats);
  const size_t NEED = o;
  if (NEED > ws_size) {
    stg_sentinel<<<(out_size+255)/256,256,0,stream>>>((float*)d_out, out_size);
    return;
  }

  u16* w1ihF=(u16*)(base+off_w1ih);              // [w1ihF|w1ihB] contiguous = [4096][1152]
  u16* w1ihB=(u16*)(base+off_w1ih+SZ_w1ih);
  u16* w2ihF=(u16*)(base+off_w1ih);              // alias after L1 proj: [4096][1024]
  u16* w2ihB=(u16*)(base+off_w1ih+SZ_w2ih);
  u16* whhAll=(u16*)(base+off_whh);
  float* biasAll=(float*)(base+off_bias);
  u16* w2gT=(u16*)(base+off_w2gT);
  u16* h1T =(u16*)(base+off_h1T);
  u16* h2T =(u16*)(base+off_h2T);
  float* part=(float*)(base+off_part);
  float* stats=(float*)(base+off_stat);
  u16* hs0=(u16*)(base+off_hs0);
  u16* hs1=(u16*)(base+off_hs1);
  float* cs=(float*)(base+off_cs);
  u16* xprAll=(u16*)(base+off_R12);              // merged [23040][4096]
  u16* xpB_=(u16*)(base+off_R12);                // GAT-phase aliases within R12
  u16* aggB=(u16*)(base+off_R12+SZ_gat);
  u16* hB  =(u16*)(base+off_R12+2*SZ_gat);
  float* ssrc=(float*)(base+off_R12+3*SZ_gat);
  float* sdst=(float*)(base+off_R12+3*SZ_gat+SZ_sc);
  u16* mid =(u16*)(base+off_R12);                // head phase: xpr dead
  u16* feats=(u16*)(base+off_R3);
  u16* seq  =(u16*)(base+off_R3);

  // ---- prep ----
  stg_permute_w<<<G4*IN1P/256,256,0,stream>>>(l1f_wih,w1ihF,IN1,IN1P);
  stg_permute_w<<<G4*IN1P/256,256,0,stream>>>(l1b_wih,w1ihB,IN1,IN1P);
  stg_permute_w<<<G4*LH/256,256,0,stream>>>(l1f_whh,whhAll+0*(size_t)G4*LH,LH,LH);
  stg_permute_w<<<G4*LH/256,256,0,stream>>>(l1b_whh,whhAll+1*(size_t)G4*LH,LH,LH);
  stg_permute_w<<<G4*LH/256,256,0,stream>>>(l2f_whh,whhAll+2*(size_t)G4*LH,LH,LH);
  stg_permute_w<<<G4*LH/256,256,0,stream>>>(l2b_whh,whhAll+3*(size_t)G4*LH,LH,LH);
  stg_prep_bias<<<G4/256,256,0,stream>>>(l1f_bih,l1f_bhh,biasAll+0*G4);
  stg_prep_bias<<<G4/256,256,0,stream>>>(l1b_bih,l1b_bhh,biasAll+1*G4);
  stg_prep_bias<<<G4/256,256,0,stream>>>(l2f_bih,l2f_bhh,biasAll+2*G4);
  stg_prep_bias<<<G4/256,256,0,stream>>>(l2b_bih,l2b_bhh,biasAll+3*G4);
  stg_transpose_pad<<<64*64/256,256,0,stream>>>(g2W,w2gT,64,64,64);
  stg_transpose_pad<<<256*1024/256,256,0,stream>>>(h1w,h1T,1024,256,256);
  stg_transpose_pad<<<64*256/256,256,0,stream>>>(h2w,h2T,256,57,64);

  // ---- GAT layer 1 (scores fused into xp) ----
  stg_gat1_xp<<<NN*64/256,256,0,stream>>>(x,g1W,xpB_,g1as,g1ad,ssrc,sdst);
  stg_gat_agg<<<NN/4,256,0,stream>>>(xpB_,ssrc,sdst,g1b,aggB);
  stg_bn_part<<<256,256,0,stream>>>(aggB,part);
  stg_bn_fin<<<1,64,0,stream>>>(part,bn1g,bn1b,stats);
  stg_bn_apply<<<NN*64/256,256,0,stream>>>(aggB,stats,hB);

  // ---- GAT layer 2 ----
  stg_gemm_bt<128,64,2,2,0><<<dim3(1,NN/128),256,0,stream>>>(hB,64,w2gT,64,xpB_,64,64,nullptr);
  stg_scores<<<NN/4,256,0,stream>>>(xpB_,g2as,g2ad,ssrc,sdst);
  stg_gat_agg<<<NN/4,256,0,stream>>>(xpB_,ssrc,sdst,g2b,aggB);
  stg_bn_part<<<256,256,0,stream>>>(aggB,part);
  stg_bn_fin<<<1,64,0,stream>>>(part,bn2g,bn2b,stats);
  stg_bn_apply<<<NN*64/256,256,0,stream>>>(aggB,stats,hB);

  // ---- feats ----
  stg_build_feats<<<SEQR*IN1P/256,256,0,stream>>>(hB,x,feats);

  // ---- BiLSTM layer 1 projection: ONE merged 128x256 GEMM (8 waves) ----
  stg_gemm_bt<128,256,2,4,0><<<dim3(G8/256,SEQR/128),512,0,stream>>>(feats,IN1P,w1ihF,IN1P,xprAll,G8,IN1P,nullptr);
  stg_permute_w<<<G4*1024/256,256,0,stream>>>(l2f_wih,w2ihF,1024,1024);
  stg_permute_w<<<G4*1024/256,256,0,stream>>>(l2b_wih,w2ihB,1024,1024);

  hipMemsetAsync(hs0,0,SZ_hs,stream);
  hipMemsetAsync(cs,0,SZ_cs,stream);
  for(int t=0;t<T_;++t){
    u16* hp=(t&1)?hs1:hs0; u16* hc=(t&1)?hs0:hs1;
    stg_lstm_step<<<dim3(B_/64,G4/64,2),512,0,stream>>>(hp,hc,cs,whhAll,xprAll,biasAll,seq,t);
  }

  // ---- BiLSTM layer 2: merged projection ----
  stg_gemm_bt<128,256,2,4,0><<<dim3(G8/256,SEQR/128),512,0,stream>>>(seq,1024,w2ihF,1024,xprAll,G8,1024,nullptr);
  hipMemsetAsync(hs0,0,SZ_hs,stream);
  hipMemsetAsync(cs,0,SZ_cs,stream);
  for(int t=0;t<T_;++t){
    u16* hp=(t&1)?hs1:hs0; u16* hc=(t&1)?hs0:hs1;
    stg_lstm_step<<<dim3(B_/64,G4/64,2),512,0,stream>>>(hp,hc,cs,whhAll+(size_t)2*G4*LH,xprAll,biasAll+2*G4,seq,t);
  }

  // ---- heads ----
  stg_gemm_bt<128,128,2,2,1><<<dim3(256/128,SEQR/128),256,0,stream>>>(seq,1024,h1T,1024,mid,256,1024,h1b);
  stg_gemm_bt<128,64,2,2,2><<<dim3(1,SEQR/128),256,0,stream>>>(mid,256,h2T,256,d_out,OUT_,256,h2b);
}